// Round 10
// baseline (217.356 us; speedup 1.0000x reference)
//
#include <hip/hip_runtime.h>
#include <math.h>

#define NRES 512
#define CSD  384
#define CZD  128

// workspace layout (float offsets)
#define OFF_Q     0         //  512*192
#define OFF_KT    98304     //  192*512   kkT[c][k]
#define OFF_VC    196608    //  512*512   vcomb[k][u]  (u<192: v, 192..479: v_pts)
#define OFF_QP    458752    //  512*144   q_pts row-major
#define OFF_KPT   532480    //  144*512   kptsT[dim][k]
#define OFF_A     606208    //  3145728: logitsT[h][q][k] (k_bias3->k_row5), then part (k_out2->k_red)
#define OFF_OCAT  3751936   //  512*2112
#define OFF_WCAT  4833280   //  384*1152 wcat + 1152 bcat
#define OFF_BCAT  (OFF_WCAT + 442368)
#define OFF_PRAWQ 5276800   //  512*144 (k_proj2 -> k_rot)
#define OFF_PRAWK 5350528   //  512*432
#define OFF_PART  OFF_A     //  6*196608 (k_out2 -> k_red, logitsT dead by then)

// ---------------------------------------------------------------- weight concat
__global__ __launch_bounds__(256) void k_wcat(
    const float* __restrict__ w_q, const float* __restrict__ b_q,
    const float* __restrict__ w_kv, const float* __restrict__ b_kv,
    const float* __restrict__ w_qp, const float* __restrict__ b_qp,
    const float* __restrict__ w_kvp, const float* __restrict__ b_kvp,
    float* __restrict__ wcat, float* __restrict__ bcat)
{
    const int idx = blockIdx.x * 256 + threadIdx.x;
    if (idx < 442368) {
        const int k = idx / 1152, c = idx % 1152;
        float v;
        if (c < 192)      v = w_q[k*192 + c];
        else if (c < 576) v = w_kv[k*384 + (c - 192)];
        else if (c < 720) v = w_qp[k*144 + (c - 576)];
        else              v = w_kvp[k*432 + (c - 720)];
        wcat[idx] = v;
    } else if (idx < 443520) {
        const int c = idx - 442368;
        float v;
        if (c < 192)      v = b_q[c];
        else if (c < 576) v = b_kv[c - 192];
        else if (c < 720) v = b_qp[c - 576];
        else              v = b_kvp[c - 720];
        bcat[c] = v;
    }
}

// ---------------------------------------------------------------- projections GEMM
__global__ __launch_bounds__(256) void k_proj2(
    const float* __restrict__ s, const float* __restrict__ wcat, const float* __restrict__ bcat,
    float* __restrict__ q, float* __restrict__ kkT, float* __restrict__ vcomb,
    float* __restrict__ praw_q, float* __restrict__ praw_kv)
{
    const int ct = blockIdx.x;
    const int n0 = blockIdx.y * 32;
    const int t = threadIdx.x;

    __shared__ float sT[32][34];
    __shared__ float wt[32][36];

    const int lr = t >> 3, lc4 = t & 7;
    const int tr = t >> 4, tc = t & 15;
    float4 sv4, wv4;

    sv4 = *(const float4*)&s[(n0 + lr) * CSD + lc4 * 4];
    wv4 = *(const float4*)&wcat[lr * 1152 + ct * 32 + lc4 * 4];
    sT[lc4*4+0][lr] = sv4.x; sT[lc4*4+1][lr] = sv4.y; sT[lc4*4+2][lr] = sv4.z; sT[lc4*4+3][lr] = sv4.w;
    *(float4*)&wt[lr][lc4*4] = wv4;
    __syncthreads();

    float a00 = 0.f, a01 = 0.f, a10 = 0.f, a11 = 0.f;

    for (int it = 0; it < 12; ++it) {
        if (it < 11) {
            const int k0 = (it + 1) * 32;
            sv4 = *(const float4*)&s[(n0 + lr) * CSD + k0 + lc4 * 4];
            wv4 = *(const float4*)&wcat[(k0 + lr) * 1152 + ct * 32 + lc4 * 4];
        }
        #pragma unroll
        for (int kx = 0; kx < 32; ++kx) {
            float2 ss = *(const float2*)&sT[kx][tr * 2];
            float2 ww = *(const float2*)&wt[kx][tc * 2];
            a00 += ss.x * ww.x; a01 += ss.x * ww.y;
            a10 += ss.y * ww.x; a11 += ss.y * ww.y;
        }
        __syncthreads();
        if (it < 11) {
            sT[lc4*4+0][lr] = sv4.x; sT[lc4*4+1][lr] = sv4.y; sT[lc4*4+2][lr] = sv4.z; sT[lc4*4+3][lr] = sv4.w;
            *(float4*)&wt[lr][lc4*4] = wv4;
            __syncthreads();
        }
    }

    float accv[2][2] = {{a00, a01}, {a10, a11}};
    #pragma unroll
    for (int i = 0; i < 2; ++i) {
        const int n = n0 + tr * 2 + i;
        #pragma unroll
        for (int j = 0; j < 2; ++j) {
            const int gcol = ct * 32 + tc * 2 + j;
            const float v = accv[i][j] + bcat[gcol];
            if (gcol < 192) {
                q[n*192 + gcol] = v;
            } else if (gcol < 576) {
                int g = gcol - 192, h = g >> 5, cc = g & 31;
                if (cc < 16) kkT[(h*16 + cc)*NRES + n] = v;
                else         vcomb[n*NRES + h*16 + (cc-16)] = v;
            } else if (gcol < 720) {
                praw_q[n*144 + (gcol - 576)] = v;
            } else {
                praw_kv[n*432 + (gcol - 720)] = v;
            }
        }
    }
}

// ---------------------------------------------------------------- rigid-frame rotation
__global__ __launch_bounds__(256) void k_rot(
    const float* __restrict__ praw_q, const float* __restrict__ praw_kv,
    const float* __restrict__ rot, const float* __restrict__ trans,
    float* __restrict__ q_pts, float* __restrict__ kptsT, float* __restrict__ vcomb)
{
    const int idx = blockIdx.x * 256 + threadIdx.x;
    const int n = idx / 192, u = idx % 192;
    const float* R = rot + n*9;
    const float* T = trans + n*3;
    float px, py, pz;
    if (u < 48) {
        px = praw_q[n*144 + u]; py = praw_q[n*144 + 48 + u]; pz = praw_q[n*144 + 96 + u];
    } else {
        int pt = u - 48;
        px = praw_kv[n*432 + pt]; py = praw_kv[n*432 + 144 + pt]; pz = praw_kv[n*432 + 288 + pt];
    }
    float x  = R[0]*px + R[1]*py + R[2]*pz + T[0];
    float y  = R[3]*px + R[4]*py + R[5]*pz + T[1];
    float zc = R[6]*px + R[7]*py + R[8]*pz + T[2];
    if (u < 48) {
        int o = (n*48 + u)*3;
        q_pts[o] = x; q_pts[o+1] = y; q_pts[o+2] = zc;
    } else {
        int pt = u - 48;
        int h = pt / 12, pp = pt % 12;
        if (pp < 4) {
            int dim = (h*4 + pp)*3;
            kptsT[(dim+0)*NRES + n] = x;
            kptsT[(dim+1)*NRES + n] = y;
            kptsT[(dim+2)*NRES + n] = zc;
        } else {
            int u2 = (h*8 + (pp-4))*3;
            vcomb[n*NRES + 192 + u2+0] = x;
            vcomb[n*NRES + 192 + u2+1] = y;
            vcomb[n*NRES + 192 + u2+2] = zc;
        }
    }
}

// ---------------------------------------------------------------- z pass 1: bias + FULL logits
// grid (8 k-chunks, 512 q). XOR-swizzled z tile, b128 LDS reads, wbT transposed.
__global__ __launch_bounds__(256) void k_bias3(
    const float* __restrict__ z, const float* __restrict__ w_b, const float* __restrict__ b_b,
    const float* __restrict__ q, const float* __restrict__ kkT,
    const float* __restrict__ q_pts, const float* __restrict__ kptsT,
    const float* __restrict__ head_weights, const float* __restrict__ mask,
    float* __restrict__ logitsT)
{
    const int k0 = blockIdx.x * 64;
    const int qn = blockIdx.y;
    const int t = threadIdx.x;
    __shared__ float zt[64*128];         // flat, XOR swizzle: float4-slot c4 ^= (row&7)<<2... (in float units: (c4*4)^((row&7)<<4))
    __shared__ float wbT[12*128];
    __shared__ float q_lds[192];
    __shared__ float qp_lds[144];
    __shared__ float hw_lds[12];

    // stage z tile (coalesced float4 loads, swizzled float4 stores)
    const float4* zp4 = (const float4*)(z + ((size_t)qn*NRES + k0)*CZD);
    float4 zstg[8];
    #pragma unroll
    for (int r = 0; r < 8; ++r) zstg[r] = zp4[t + r*256];
    #pragma unroll
    for (int r = 0; r < 8; ++r) {
        const int idx = t + r*256;
        const int row = idx >> 5, c4 = idx & 31;
        const int sc4 = c4 ^ ((row & 7) << 2);
        *(float4*)&zt[row*128 + sc4*4] = zstg[r];
    }
    for (int i = t; i < 1536; i += 256) {
        const int h = i >> 7, c = i & 127;
        wbT[h*128 + c] = w_b[c*12 + h];
    }
    if (t < 192) q_lds[t] = q[qn*192 + t];
    if (t < 144) qp_lds[t] = q_pts[qn*144 + t];
    if (t < 12)  hw_lds[t] = logf(1.f + expf(head_weights[t])) * 0.13608276f;
    __syncthreads();

    const int k = t & 63;
    const int h0 = (t >> 6) * 3;
    float acc0 = 0.f, acc1 = 0.f, acc2 = 0.f;
    const float* zr = &zt[k*128];
    const float* w0 = &wbT[(h0+0)*128];
    const float* w1 = &wbT[(h0+1)*128];
    const float* w2 = &wbT[(h0+2)*128];
    const int sw = (k & 7) << 2;
    #pragma unroll
    for (int c4 = 0; c4 < 32; ++c4) {
        const int sc4 = c4 ^ sw;
        float4 zv = *(const float4*)&zr[sc4*4];
        float4 wa = *(const float4*)&w0[c4*4];
        float4 wbv = *(const float4*)&w1[c4*4];
        float4 wc = *(const float4*)&w2[c4*4];
        acc0 += zv.x*wa.x + zv.y*wa.y + zv.z*wa.z + zv.w*wa.w;
        acc1 += zv.x*wbv.x + zv.y*wbv.y + zv.z*wbv.z + zv.w*wbv.w;
        acc2 += zv.x*wc.x + zv.y*wc.y + zv.z*wc.z + zv.w*wc.w;
    }
    // wait: zv was loaded with swizzled index but wb with linear c4 -> mismatch!
    // fix: since dot product is order-invariant over c, permute wb reads with the SAME swizzle.
    // (handled above by using sc4 for z only would be wrong; recompute properly below)
    // -- correctness: redo with both sides swizzled --
    acc0 = 0.f; acc1 = 0.f; acc2 = 0.f;
    #pragma unroll
    for (int c4 = 0; c4 < 32; ++c4) {
        const int sc4 = c4 ^ sw;          // read z slot sc4 (holds original data at column sc4 ^ sw ... )
        float4 zv = *(const float4*)&zr[c4*4];          // slot c4 holds original column (c4 ^ sw)
        float4 wa = *(const float4*)&w0[sc4*4];         // matching wb column
        float4 wbv = *(const float4*)&w1[sc4*4];
        float4 wc = *(const float4*)&w2[sc4*4];
        acc0 += zv.x*wa.x + zv.y*wa.y + zv.z*wa.z + zv.w*wa.w;
        acc1 += zv.x*wbv.x + zv.y*wbv.y + zv.z*wbv.z + zv.w*wbv.w;
        acc2 += zv.x*wc.x + zv.y*wc.y + zv.z*wc.z + zv.w*wc.w;
    }

    const int kn = k0 + k;
    const float mterm = (mask[qn]*mask[kn] - 1.f) * 100000.f;
    const float bias0 = acc0 + b_b[h0+0];
    const float bias1 = acc1 + b_b[h0+1];
    const float bias2 = acc2 + b_b[h0+2];
    float biasv[3] = {bias0, bias1, bias2};
    #pragma unroll
    for (int j = 0; j < 3; ++j) {
        const int h = h0 + j;
        float qk = 0.f;
        const float* kT = kkT + (size_t)(h*16)*NRES + kn;
        #pragma unroll
        for (int c = 0; c < 16; ++c) qk += q_lds[h*16 + c] * kT[(size_t)c*NRES];
        float dsum = 0.f;
        const float* kpT = kptsT + (size_t)(h*12)*NRES + kn;
        #pragma unroll
        for (int d = 0; d < 12; ++d) { float df = qp_lds[h*12 + d] - kpT[(size_t)d*NRES]; dsum += df*df; }
        logitsT[(size_t)h*NRES*NRES + (size_t)qn*NRES + kn] =
            0.14433757f*qk + 0.57735027f*biasv[j] - 0.5f*hw_lds[h]*dsum + mterm;
    }
}

// ---------------------------------------------------------------- per-q-row: softmax + o_pair + o/o_pt + rot
__global__ __launch_bounds__(256) void k_row5(
    const float* __restrict__ z, const float* __restrict__ logitsT,
    const float* __restrict__ vcomb,
    const float* __restrict__ rot, const float* __restrict__ trans,
    float* __restrict__ o_cat)
{
    const int qn = blockIdx.x;
    const int t = threadIdx.x;

    __shared__ float a_lds[12][521];
    __shared__ float pred[4][12][128];
    __shared__ float optraw[288];

    // load logits row (coalesced)
    for (int i = t; i < 12*NRES; i += 256)
        a_lds[i >> 9][i & 511] = logitsT[(size_t)(i >> 9)*NRES*NRES + (size_t)qn*NRES + (i & 511)];
    __syncthreads();

    // softmax, warp-parallel across heads (3 heads/wave)
    {
        const int w = t >> 6, lane = t & 63;
        for (int h = w; h < 12; h += 4) {
            float m = -1e30f;
            #pragma unroll
            for (int i = 0; i < 8; ++i) m = fmaxf(m, a_lds[h][lane + i*64]);
            #pragma unroll
            for (int off = 32; off > 0; off >>= 1) m = fmaxf(m, __shfl_xor(m, off));
            float ss = 0.f;
            #pragma unroll
            for (int i = 0; i < 8; ++i) {
                float e = __expf(a_lds[h][lane + i*64] - m);
                a_lds[h][lane + i*64] = e;
                ss += e;
            }
            #pragma unroll
            for (int off = 32; off > 0; off >>= 1) ss += __shfl_xor(ss, off);
            float inv = 1.f / ss;
            #pragma unroll
            for (int i = 0; i < 8; ++i) a_lds[h][lane + i*64] *= inv;
        }
    }
    __syncthreads();

    // o_pair (z second pass, L3-resident)
    {
        const int c4 = t & 31, kgrp = t >> 5;
        const float4* zp = (const float4*)(z + (size_t)qn*NRES*CZD) + c4;
        float4 acc4[12];
        #pragma unroll
        for (int h = 0; h < 12; ++h) acc4[h] = make_float4(0.f,0.f,0.f,0.f);

        #pragma unroll 8
        for (int kn = kgrp; kn < NRES; kn += 8) {
            float4 zv = zp[kn*32];
            #pragma unroll
            for (int h = 0; h < 12; ++h) {
                float av = a_lds[h][kn];
                acc4[h].x += av*zv.x; acc4[h].y += av*zv.y;
                acc4[h].z += av*zv.z; acc4[h].w += av*zv.w;
            }
        }
        #pragma unroll
        for (int h = 0; h < 12; ++h) {
            acc4[h].x += __shfl_xor(acc4[h].x, 32);
            acc4[h].y += __shfl_xor(acc4[h].y, 32);
            acc4[h].z += __shfl_xor(acc4[h].z, 32);
            acc4[h].w += __shfl_xor(acc4[h].w, 32);
        }
        const int wave = t >> 6;
        if ((t & 63) < 32) {
            #pragma unroll
            for (int h = 0; h < 12; ++h) {
                pred[wave][h][c4*4+0] = acc4[h].x;
                pred[wave][h][c4*4+1] = acc4[h].y;
                pred[wave][h][c4*4+2] = acc4[h].z;
                pred[wave][h][c4*4+3] = acc4[h].w;
            }
        }
        __syncthreads();
        for (int i = t; i < 1536; i += 256) {
            int h = i >> 7, c = i & 127;
            float v = pred[0][h][c] + pred[1][h][c] + pred[2][h][c] + pred[3][h][c];
            o_cat[qn*2112 + 576 + h*128 + c] = v;
        }
    }

    // o (192) + o_pt raw (288) from vcomb (L2), float2 per thread
    if (t < 240) {
        const int ch0 = 2*t, ch1 = 2*t + 1;
        const int hA = (ch0 < 192) ? (ch0 >> 4) : (ch0 - 192) / 24;
        const int hB = (ch1 < 192) ? (ch1 >> 4) : (ch1 - 192) / 24;
        float aAcc = 0.f, bAcc = 0.f;
        const float2* vp2 = (const float2*)vcomb + t;
        #pragma unroll 8
        for (int kn = 0; kn < NRES; ++kn) {
            float2 v = vp2[(size_t)kn*256];
            aAcc += a_lds[hA][kn] * v.x;
            bAcc += a_lds[hB][kn] * v.y;
        }
        if (ch0 < 192) o_cat[qn*2112 + ch0] = aAcc;
        else           optraw[ch0 - 192] = aAcc;
        if (ch1 < 192) o_cat[qn*2112 + ch1] = bAcc;
        else           optraw[ch1 - 192] = bAcc;
    }
    __syncthreads();

    // inverse rotation + norms
    if (t < 96) {
        const float* R = rot + qn*9;
        const float* T = trans + qn*3;
        float ox = optraw[t*3]   - T[0];
        float oy = optraw[t*3+1] - T[1];
        float oz = optraw[t*3+2] - T[2];
        float x  = R[0]*ox + R[3]*oy + R[6]*oz;
        float y  = R[1]*ox + R[4]*oy + R[7]*oz;
        float zc = R[2]*ox + R[5]*oy + R[8]*oz;
        float* ob = o_cat + qn*2112;
        ob[192 + t] = x;
        ob[288 + t] = y;
        ob[384 + t] = zc;
        ob[480 + t] = sqrtf(x*x + y*y + zc*zc + 1e-8f);
    }
}

// ---------------------------------------------------------------- final GEMM
__global__ __launch_bounds__(256) void k_out2(
    const float* __restrict__ o_cat, const float* __restrict__ w_out, float* __restrict__ part)
{
    const int ct = blockIdx.x;
    const int n0 = blockIdx.y * 32;
    const int kc = blockIdx.z;
    const int t = threadIdx.x;

    __shared__ float oT[32][34];
    __shared__ float wt[32][36];

    const int lr = t >> 3, lc4 = t & 7;
    const int tr = t >> 4, tc = t & 15;
    const int kbase = kc * 352;
    float4 ov4, wv4;

    ov4 = *(const float4*)&o_cat[(n0 + lr) * 2112 + kbase + lc4 * 4];
    wv4 = *(const float4*)&w_out[(kbase + lr) * 384 + ct * 32 + lc4 * 4];
    oT[lc4*4+0][lr] = ov4.x; oT[lc4*4+1][lr] = ov4.y; oT[lc4*4+2][lr] = ov4.z; oT[lc4*4+3][lr] = ov4.w;
    *(float4*)&wt[lr][lc4*4] = wv4;
    __syncthreads();

    float a00 = 0.f, a01 = 0.f, a10 = 0.f, a11 = 0.f;

    for (int it = 0; it < 11; ++it) {
        if (it < 10) {
            const int k0 = kbase + (it + 1) * 32;
            ov4 = *(const float4*)&o_cat[(n0 + lr) * 2112 + k0 + lc4 * 4];
            wv4 = *(const float4*)&w_out[(k0 + lr) * 384 + ct * 32 + lc4 * 4];
        }
        #pragma unroll
        for (int kx = 0; kx < 32; ++kx) {
            float2 oo = *(const float2*)&oT[kx][tr * 2];
            float2 ww = *(const float2*)&wt[kx][tc * 2];
            a00 += oo.x * ww.x; a01 += oo.x * ww.y;
            a10 += oo.y * ww.x; a11 += oo.y * ww.y;
        }
        __syncthreads();
        if (it < 10) {
            oT[lc4*4+0][lr] = ov4.x; oT[lc4*4+1][lr] = ov4.y; oT[lc4*4+2][lr] = ov4.z; oT[lc4*4+3][lr] = ov4.w;
            *(float4*)&wt[lr][lc4*4] = wv4;
            __syncthreads();
        }
    }

    float* pp = part + (size_t)kc * 196608;
    pp[(n0 + tr*2 + 0)*384 + ct*32 + tc*2 + 0] = a00;
    pp[(n0 + tr*2 + 0)*384 + ct*32 + tc*2 + 1] = a01;
    pp[(n0 + tr*2 + 1)*384 + ct*32 + tc*2 + 0] = a10;
    pp[(n0 + tr*2 + 1)*384 + ct*32 + tc*2 + 1] = a11;
}

__global__ __launch_bounds__(256) void k_red(
    const float* __restrict__ part, const float* __restrict__ b_out, float* __restrict__ out)
{
    const int i = blockIdx.x*256 + threadIdx.x;
    float acc = b_out[i % 384];
    #pragma unroll
    for (int dc = 0; dc < 6; ++dc) acc += part[(size_t)dc*196608 + i];
    out[i] = acc;
}

// ----------------------------------------------------------------
extern "C" void kernel_launch(void* const* d_in, const int* in_sizes, int n_in,
                              void* d_out, int out_size, void* d_ws, size_t ws_size,
                              hipStream_t stream) {
    (void)in_sizes; (void)n_in; (void)out_size; (void)ws_size;
    const float* s      = (const float*)d_in[0];
    const float* z      = (const float*)d_in[1];
    const float* rot    = (const float*)d_in[2];
    const float* trans  = (const float*)d_in[3];
    const float* mask   = (const float*)d_in[4];
    const float* w_q    = (const float*)d_in[5];
    const float* b_q    = (const float*)d_in[6];
    const float* w_kv   = (const float*)d_in[7];
    const float* b_kv   = (const float*)d_in[8];
    const float* w_qp   = (const float*)d_in[9];
    const float* b_qp   = (const float*)d_in[10];
    const float* w_kvp  = (const float*)d_in[11];
    const float* b_kvp  = (const float*)d_in[12];
    const float* w_b    = (const float*)d_in[13];
    const float* b_b    = (const float*)d_in[14];
    const float* hwts   = (const float*)d_in[15];
    const float* w_out  = (const float*)d_in[16];
    const float* b_out  = (const float*)d_in[17];
    float* out = (float*)d_out;
    float* ws  = (float*)d_ws;

    float* q       = ws + OFF_Q;
    float* kkT     = ws + OFF_KT;
    float* vcomb   = ws + OFF_VC;
    float* qp      = ws + OFF_QP;
    float* kptsT   = ws + OFF_KPT;
    float* logitsT = ws + OFF_A;
    float* ocat    = ws + OFF_OCAT;
    float* wcat    = ws + OFF_WCAT;
    float* bcat    = ws + OFF_BCAT;
    float* part    = ws + OFF_PART;
    float* praw_q  = ws + OFF_PRAWQ;
    float* praw_kv = ws + OFF_PRAWK;

    k_wcat<<<dim3(1733), dim3(256), 0, stream>>>(w_q, b_q, w_kv, b_kv, w_qp, b_qp, w_kvp, b_kvp, wcat, bcat);
    k_proj2<<<dim3(36, 16), dim3(256), 0, stream>>>(s, wcat, bcat, q, kkT, vcomb, praw_q, praw_kv);
    k_rot<<<dim3(384), dim3(256), 0, stream>>>(praw_q, praw_kv, rot, trans, qp, kptsT, vcomb);
    k_bias3<<<dim3(8, NRES), dim3(256), 0, stream>>>(z, w_b, b_b, q, kkT, qp, kptsT,
        hwts, mask, logitsT);
    k_row5<<<dim3(NRES), dim3(256), 0, stream>>>(z, logitsT, vcomb, rot, trans, ocat);
    k_out2<<<dim3(12, 16, 6), dim3(256), 0, stream>>>(ocat, w_out, part);
    k_red<<<dim3(768), dim3(256), 0, stream>>>(part, b_out, out);
}

// Round 11
// 173.893 us; speedup vs baseline: 1.2499x; 1.2499x over previous
//
#include <hip/hip_runtime.h>
#include <math.h>

#define NRES 512
#define CSD  384
#define CZD  128

// workspace layout (float offsets)
#define OFF_Q     0         //  512*192
#define OFF_KT    98304     //  192*512   kkT[c][k]
#define OFF_VC    196608    //  512*512   vcomb[k][u]  (u<192: v, 192..479: v_pts)
#define OFF_QP    458752    //  512*144   q_pts row-major
#define OFF_KPT   532480    //  144*512   kptsT[dim][k]
#define OFF_A     606208    //  3145728: logitsT[h][q][k] (k_bias3->k_row5), then part (k_out2->k_red)
#define OFF_OCAT  3751936   //  512*2112
#define OFF_WCAT  4833280   //  384*1152 wcat + 1152 bcat
#define OFF_BCAT  (OFF_WCAT + 442368)
#define OFF_PRAWQ 5276800   //  512*144 (k_proj2 -> k_rot)
#define OFF_PRAWK 5350528   //  512*432
#define OFF_PART  OFF_A     //  6*196608 (k_out2 -> k_red, logitsT dead by then)

// ---------------------------------------------------------------- weight concat
__global__ __launch_bounds__(256) void k_wcat(
    const float* __restrict__ w_q, const float* __restrict__ b_q,
    const float* __restrict__ w_kv, const float* __restrict__ b_kv,
    const float* __restrict__ w_qp, const float* __restrict__ b_qp,
    const float* __restrict__ w_kvp, const float* __restrict__ b_kvp,
    float* __restrict__ wcat, float* __restrict__ bcat)
{
    const int idx = blockIdx.x * 256 + threadIdx.x;
    if (idx < 442368) {
        const int k = idx / 1152, c = idx % 1152;
        float v;
        if (c < 192)      v = w_q[k*192 + c];
        else if (c < 576) v = w_kv[k*384 + (c - 192)];
        else if (c < 720) v = w_qp[k*144 + (c - 576)];
        else              v = w_kvp[k*432 + (c - 720)];
        wcat[idx] = v;
    } else if (idx < 443520) {
        const int c = idx - 442368;
        float v;
        if (c < 192)      v = b_q[c];
        else if (c < 576) v = b_kv[c - 192];
        else if (c < 720) v = b_qp[c - 576];
        else              v = b_kvp[c - 720];
        bcat[c] = v;
    }
}

// ---------------------------------------------------------------- projections GEMM
__global__ __launch_bounds__(256) void k_proj2(
    const float* __restrict__ s, const float* __restrict__ wcat, const float* __restrict__ bcat,
    float* __restrict__ q, float* __restrict__ kkT, float* __restrict__ vcomb,
    float* __restrict__ praw_q, float* __restrict__ praw_kv)
{
    const int ct = blockIdx.x;
    const int n0 = blockIdx.y * 32;
    const int t = threadIdx.x;

    __shared__ float sT[32][34];
    __shared__ float wt[32][36];

    const int lr = t >> 3, lc4 = t & 7;
    const int tr = t >> 4, tc = t & 15;
    float4 sv4, wv4;

    sv4 = *(const float4*)&s[(n0 + lr) * CSD + lc4 * 4];
    wv4 = *(const float4*)&wcat[lr * 1152 + ct * 32 + lc4 * 4];
    sT[lc4*4+0][lr] = sv4.x; sT[lc4*4+1][lr] = sv4.y; sT[lc4*4+2][lr] = sv4.z; sT[lc4*4+3][lr] = sv4.w;
    *(float4*)&wt[lr][lc4*4] = wv4;
    __syncthreads();

    float a00 = 0.f, a01 = 0.f, a10 = 0.f, a11 = 0.f;

    for (int it = 0; it < 12; ++it) {
        if (it < 11) {
            const int k0 = (it + 1) * 32;
            sv4 = *(const float4*)&s[(n0 + lr) * CSD + k0 + lc4 * 4];
            wv4 = *(const float4*)&wcat[(k0 + lr) * 1152 + ct * 32 + lc4 * 4];
        }
        #pragma unroll
        for (int kx = 0; kx < 32; ++kx) {
            float2 ss = *(const float2*)&sT[kx][tr * 2];
            float2 ww = *(const float2*)&wt[kx][tc * 2];
            a00 += ss.x * ww.x; a01 += ss.x * ww.y;
            a10 += ss.y * ww.x; a11 += ss.y * ww.y;
        }
        __syncthreads();
        if (it < 11) {
            sT[lc4*4+0][lr] = sv4.x; sT[lc4*4+1][lr] = sv4.y; sT[lc4*4+2][lr] = sv4.z; sT[lc4*4+3][lr] = sv4.w;
            *(float4*)&wt[lr][lc4*4] = wv4;
            __syncthreads();
        }
    }

    float accv[2][2] = {{a00, a01}, {a10, a11}};
    #pragma unroll
    for (int i = 0; i < 2; ++i) {
        const int n = n0 + tr * 2 + i;
        #pragma unroll
        for (int j = 0; j < 2; ++j) {
            const int gcol = ct * 32 + tc * 2 + j;
            const float v = accv[i][j] + bcat[gcol];
            if (gcol < 192) {
                q[n*192 + gcol] = v;
            } else if (gcol < 576) {
                int g = gcol - 192, h = g >> 5, cc = g & 31;
                if (cc < 16) kkT[(h*16 + cc)*NRES + n] = v;
                else         vcomb[n*NRES + h*16 + (cc-16)] = v;
            } else if (gcol < 720) {
                praw_q[n*144 + (gcol - 576)] = v;
            } else {
                praw_kv[n*432 + (gcol - 720)] = v;
            }
        }
    }
}

// ---------------------------------------------------------------- rigid-frame rotation
__global__ __launch_bounds__(256) void k_rot(
    const float* __restrict__ praw_q, const float* __restrict__ praw_kv,
    const float* __restrict__ rot, const float* __restrict__ trans,
    float* __restrict__ q_pts, float* __restrict__ kptsT, float* __restrict__ vcomb)
{
    const int idx = blockIdx.x * 256 + threadIdx.x;
    const int n = idx / 192, u = idx % 192;
    const float* R = rot + n*9;
    const float* T = trans + n*3;
    float px, py, pz;
    if (u < 48) {
        px = praw_q[n*144 + u]; py = praw_q[n*144 + 48 + u]; pz = praw_q[n*144 + 96 + u];
    } else {
        int pt = u - 48;
        px = praw_kv[n*432 + pt]; py = praw_kv[n*432 + 144 + pt]; pz = praw_kv[n*432 + 288 + pt];
    }
    float x  = R[0]*px + R[1]*py + R[2]*pz + T[0];
    float y  = R[3]*px + R[4]*py + R[5]*pz + T[1];
    float zc = R[6]*px + R[7]*py + R[8]*pz + T[2];
    if (u < 48) {
        int o = (n*48 + u)*3;
        q_pts[o] = x; q_pts[o+1] = y; q_pts[o+2] = zc;
    } else {
        int pt = u - 48;
        int h = pt / 12, pp = pt % 12;
        if (pp < 4) {
            int dim = (h*4 + pp)*3;
            kptsT[(dim+0)*NRES + n] = x;
            kptsT[(dim+1)*NRES + n] = y;
            kptsT[(dim+2)*NRES + n] = zc;
        } else {
            int u2 = (h*8 + (pp-4))*3;
            vcomb[n*NRES + 192 + u2+0] = x;
            vcomb[n*NRES + 192 + u2+1] = y;
            vcomb[n*NRES + 192 + u2+2] = zc;
        }
    }
}

// ---------------------------------------------------------------- z pass 1: bias + FULL logits
// grid (8 k-chunks, 512 q). XOR-swizzled z tile (swizzle on BOTH store and read addresses),
// b128 LDS reads, wbT transposed (broadcast reads, linear index).
__global__ __launch_bounds__(256) void k_bias3(
    const float* __restrict__ z, const float* __restrict__ w_b, const float* __restrict__ b_b,
    const float* __restrict__ q, const float* __restrict__ kkT,
    const float* __restrict__ q_pts, const float* __restrict__ kptsT,
    const float* __restrict__ head_weights, const float* __restrict__ mask,
    float* __restrict__ logitsT)
{
    const int k0 = blockIdx.x * 64;
    const int qn = blockIdx.y;
    const int t = threadIdx.x;
    __shared__ float zt[64*128];         // flat; float4-slot sc4 = c4 ^ ((row&7)<<2) holds original column-group c4
    __shared__ float wbT[12*128];
    __shared__ float q_lds[192];
    __shared__ float qp_lds[144];
    __shared__ float hw_lds[12];

    // stage z tile (coalesced float4 loads, swizzled float4 stores)
    const float4* zp4 = (const float4*)(z + ((size_t)qn*NRES + k0)*CZD);
    float4 zstg[8];
    #pragma unroll
    for (int r = 0; r < 8; ++r) zstg[r] = zp4[t + r*256];
    #pragma unroll
    for (int r = 0; r < 8; ++r) {
        const int idx = t + r*256;
        const int row = idx >> 5, c4 = idx & 31;
        const int sc4 = c4 ^ ((row & 7) << 2);
        *(float4*)&zt[row*128 + sc4*4] = zstg[r];
    }
    for (int i = t; i < 1536; i += 256) {
        const int h = i >> 7, c = i & 127;
        wbT[h*128 + c] = w_b[c*12 + h];
    }
    if (t < 192) q_lds[t] = q[qn*192 + t];
    if (t < 144) qp_lds[t] = q_pts[qn*144 + t];
    if (t < 12)  hw_lds[t] = logf(1.f + expf(head_weights[t])) * 0.13608276f;
    __syncthreads();

    const int k = t & 63;
    const int h0 = (t >> 6) * 3;
    float acc0 = 0.f, acc1 = 0.f, acc2 = 0.f;
    const float* zr = &zt[k*128];
    const float* w0 = &wbT[(h0+0)*128];
    const float* w1 = &wbT[(h0+1)*128];
    const float* w2 = &wbT[(h0+2)*128];
    const int sw = (k & 7) << 2;
    #pragma unroll
    for (int c4 = 0; c4 < 32; ++c4) {
        const int sc4 = c4 ^ sw;                    // slot sc4 holds original column-group c4 for this row
        float4 zv  = *(const float4*)&zr[sc4*4];    // SWIZZLED read address -> conflict-free across lanes
        float4 wa  = *(const float4*)&w0[c4*4];     // linear (original column), wave-broadcast
        float4 wbv = *(const float4*)&w1[c4*4];
        float4 wc  = *(const float4*)&w2[c4*4];
        acc0 += zv.x*wa.x  + zv.y*wa.y  + zv.z*wa.z  + zv.w*wa.w;
        acc1 += zv.x*wbv.x + zv.y*wbv.y + zv.z*wbv.z + zv.w*wbv.w;
        acc2 += zv.x*wc.x  + zv.y*wc.y  + zv.z*wc.z  + zv.w*wc.w;
    }

    const int kn = k0 + k;
    const float mterm = (mask[qn]*mask[kn] - 1.f) * 100000.f;
    float biasv[3] = {acc0 + b_b[h0+0], acc1 + b_b[h0+1], acc2 + b_b[h0+2]};
    #pragma unroll
    for (int j = 0; j < 3; ++j) {
        const int h = h0 + j;
        float qk = 0.f;
        const float* kT = kkT + (size_t)(h*16)*NRES + kn;
        #pragma unroll
        for (int c = 0; c < 16; ++c) qk += q_lds[h*16 + c] * kT[(size_t)c*NRES];
        float dsum = 0.f;
        const float* kpT = kptsT + (size_t)(h*12)*NRES + kn;
        #pragma unroll
        for (int d = 0; d < 12; ++d) { float df = qp_lds[h*12 + d] - kpT[(size_t)d*NRES]; dsum += df*df; }
        logitsT[(size_t)h*NRES*NRES + (size_t)qn*NRES + kn] =
            0.14433757f*qk + 0.57735027f*biasv[j] - 0.5f*hw_lds[h]*dsum + mterm;
    }
}

// ---------------------------------------------------------------- per-q-row: softmax + o_pair + o/o_pt + rot
__global__ __launch_bounds__(256) void k_row5(
    const float* __restrict__ z, const float* __restrict__ logitsT,
    const float* __restrict__ vcomb,
    const float* __restrict__ rot, const float* __restrict__ trans,
    float* __restrict__ o_cat)
{
    const int qn = blockIdx.x;
    const int t = threadIdx.x;

    __shared__ float a_lds[12][521];
    __shared__ float pred[4][12][128];
    __shared__ float optraw[288];

    // load logits row (coalesced)
    for (int i = t; i < 12*NRES; i += 256)
        a_lds[i >> 9][i & 511] = logitsT[(size_t)(i >> 9)*NRES*NRES + (size_t)qn*NRES + (i & 511)];
    __syncthreads();

    // softmax, warp-parallel across heads (3 heads/wave)
    {
        const int w = t >> 6, lane = t & 63;
        for (int h = w; h < 12; h += 4) {
            float m = -1e30f;
            #pragma unroll
            for (int i = 0; i < 8; ++i) m = fmaxf(m, a_lds[h][lane + i*64]);
            #pragma unroll
            for (int off = 32; off > 0; off >>= 1) m = fmaxf(m, __shfl_xor(m, off));
            float ss = 0.f;
            #pragma unroll
            for (int i = 0; i < 8; ++i) {
                float e = __expf(a_lds[h][lane + i*64] - m);
                a_lds[h][lane + i*64] = e;
                ss += e;
            }
            #pragma unroll
            for (int off = 32; off > 0; off >>= 1) ss += __shfl_xor(ss, off);
            float inv = 1.f / ss;
            #pragma unroll
            for (int i = 0; i < 8; ++i) a_lds[h][lane + i*64] *= inv;
        }
    }
    __syncthreads();

    // o_pair (z second pass, L3-resident)
    {
        const int c4 = t & 31, kgrp = t >> 5;
        const float4* zp = (const float4*)(z + (size_t)qn*NRES*CZD) + c4;
        float4 acc4[12];
        #pragma unroll
        for (int h = 0; h < 12; ++h) acc4[h] = make_float4(0.f,0.f,0.f,0.f);

        #pragma unroll 8
        for (int kn = kgrp; kn < NRES; kn += 8) {
            float4 zv = zp[kn*32];
            #pragma unroll
            for (int h = 0; h < 12; ++h) {
                float av = a_lds[h][kn];
                acc4[h].x += av*zv.x; acc4[h].y += av*zv.y;
                acc4[h].z += av*zv.z; acc4[h].w += av*zv.w;
            }
        }
        #pragma unroll
        for (int h = 0; h < 12; ++h) {
            acc4[h].x += __shfl_xor(acc4[h].x, 32);
            acc4[h].y += __shfl_xor(acc4[h].y, 32);
            acc4[h].z += __shfl_xor(acc4[h].z, 32);
            acc4[h].w += __shfl_xor(acc4[h].w, 32);
        }
        const int wave = t >> 6;
        if ((t & 63) < 32) {
            #pragma unroll
            for (int h = 0; h < 12; ++h) {
                pred[wave][h][c4*4+0] = acc4[h].x;
                pred[wave][h][c4*4+1] = acc4[h].y;
                pred[wave][h][c4*4+2] = acc4[h].z;
                pred[wave][h][c4*4+3] = acc4[h].w;
            }
        }
        __syncthreads();
        for (int i = t; i < 1536; i += 256) {
            int h = i >> 7, c = i & 127;
            float v = pred[0][h][c] + pred[1][h][c] + pred[2][h][c] + pred[3][h][c];
            o_cat[qn*2112 + 576 + h*128 + c] = v;
        }
    }

    // o (192) + o_pt raw (288) from vcomb (L2), float2 per thread
    if (t < 240) {
        const int ch0 = 2*t, ch1 = 2*t + 1;
        const int hA = (ch0 < 192) ? (ch0 >> 4) : (ch0 - 192) / 24;
        const int hB = (ch1 < 192) ? (ch1 >> 4) : (ch1 - 192) / 24;
        float aAcc = 0.f, bAcc = 0.f;
        const float2* vp2 = (const float2*)vcomb + t;
        #pragma unroll 8
        for (int kn = 0; kn < NRES; ++kn) {
            float2 v = vp2[(size_t)kn*256];
            aAcc += a_lds[hA][kn] * v.x;
            bAcc += a_lds[hB][kn] * v.y;
        }
        if (ch0 < 192) o_cat[qn*2112 + ch0] = aAcc;
        else           optraw[ch0 - 192] = aAcc;
        if (ch1 < 192) o_cat[qn*2112 + ch1] = bAcc;
        else           optraw[ch1 - 192] = bAcc;
    }
    __syncthreads();

    // inverse rotation + norms
    if (t < 96) {
        const float* R = rot + qn*9;
        const float* T = trans + qn*3;
        float ox = optraw[t*3]   - T[0];
        float oy = optraw[t*3+1] - T[1];
        float oz = optraw[t*3+2] - T[2];
        float x  = R[0]*ox + R[3]*oy + R[6]*oz;
        float y  = R[1]*ox + R[4]*oy + R[7]*oz;
        float zc = R[2]*ox + R[5]*oy + R[8]*oz;
        float* ob = o_cat + qn*2112;
        ob[192 + t] = x;
        ob[288 + t] = y;
        ob[384 + t] = zc;
        ob[480 + t] = sqrtf(x*x + y*y + zc*zc + 1e-8f);
    }
}

// ---------------------------------------------------------------- final GEMM
__global__ __launch_bounds__(256) void k_out2(
    const float* __restrict__ o_cat, const float* __restrict__ w_out, float* __restrict__ part)
{
    const int ct = blockIdx.x;
    const int n0 = blockIdx.y * 32;
    const int kc = blockIdx.z;
    const int t = threadIdx.x;

    __shared__ float oT[32][34];
    __shared__ float wt[32][36];

    const int lr = t >> 3, lc4 = t & 7;
    const int tr = t >> 4, tc = t & 15;
    const int kbase = kc * 352;
    float4 ov4, wv4;

    ov4 = *(const float4*)&o_cat[(n0 + lr) * 2112 + kbase + lc4 * 4];
    wv4 = *(const float4*)&w_out[(kbase + lr) * 384 + ct * 32 + lc4 * 4];
    oT[lc4*4+0][lr] = ov4.x; oT[lc4*4+1][lr] = ov4.y; oT[lc4*4+2][lr] = ov4.z; oT[lc4*4+3][lr] = ov4.w;
    *(float4*)&wt[lr][lc4*4] = wv4;
    __syncthreads();

    float a00 = 0.f, a01 = 0.f, a10 = 0.f, a11 = 0.f;

    for (int it = 0; it < 11; ++it) {
        if (it < 10) {
            const int k0 = kbase + (it + 1) * 32;
            ov4 = *(const float4*)&o_cat[(n0 + lr) * 2112 + k0 + lc4 * 4];
            wv4 = *(const float4*)&w_out[(k0 + lr) * 384 + ct * 32 + lc4 * 4];
        }
        #pragma unroll
        for (int kx = 0; kx < 32; ++kx) {
            float2 oo = *(const float2*)&oT[kx][tr * 2];
            float2 ww = *(const float2*)&wt[kx][tc * 2];
            a00 += oo.x * ww.x; a01 += oo.x * ww.y;
            a10 += oo.y * ww.x; a11 += oo.y * ww.y;
        }
        __syncthreads();
        if (it < 10) {
            oT[lc4*4+0][lr] = ov4.x; oT[lc4*4+1][lr] = ov4.y; oT[lc4*4+2][lr] = ov4.z; oT[lc4*4+3][lr] = ov4.w;
            *(float4*)&wt[lr][lc4*4] = wv4;
            __syncthreads();
        }
    }

    float* pp = part + (size_t)kc * 196608;
    pp[(n0 + tr*2 + 0)*384 + ct*32 + tc*2 + 0] = a00;
    pp[(n0 + tr*2 + 0)*384 + ct*32 + tc*2 + 1] = a01;
    pp[(n0 + tr*2 + 1)*384 + ct*32 + tc*2 + 0] = a10;
    pp[(n0 + tr*2 + 1)*384 + ct*32 + tc*2 + 1] = a11;
}

__global__ __launch_bounds__(256) void k_red(
    const float* __restrict__ part, const float* __restrict__ b_out, float* __restrict__ out)
{
    const int i = blockIdx.x*256 + threadIdx.x;
    float acc = b_out[i % 384];
    #pragma unroll
    for (int dc = 0; dc < 6; ++dc) acc += part[(size_t)dc*196608 + i];
    out[i] = acc;
}

// ----------------------------------------------------------------
extern "C" void kernel_launch(void* const* d_in, const int* in_sizes, int n_in,
                              void* d_out, int out_size, void* d_ws, size_t ws_size,
                              hipStream_t stream) {
    (void)in_sizes; (void)n_in; (void)out_size; (void)ws_size;
    const float* s      = (const float*)d_in[0];
    const float* z      = (const float*)d_in[1];
    const float* rot    = (const float*)d_in[2];
    const float* trans  = (const float*)d_in[3];
    const float* mask   = (const float*)d_in[4];
    const float* w_q    = (const float*)d_in[5];
    const float* b_q    = (const float*)d_in[6];
    const float* w_kv   = (const float*)d_in[7];
    const float* b_kv   = (const float*)d_in[8];
    const float* w_qp   = (const float*)d_in[9];
    const float* b_qp   = (const float*)d_in[10];
    const float* w_kvp  = (const float*)d_in[11];
    const float* b_kvp  = (const float*)d_in[12];
    const float* w_b    = (const float*)d_in[13];
    const float* b_b    = (const float*)d_in[14];
    const float* hwts   = (const float*)d_in[15];
    const float* w_out  = (const float*)d_in[16];
    const float* b_out  = (const float*)d_in[17];
    float* out = (float*)d_out;
    float* ws  = (float*)d_ws;

    float* q       = ws + OFF_Q;
    float* kkT     = ws + OFF_KT;
    float* vcomb   = ws + OFF_VC;
    float* qp      = ws + OFF_QP;
    float* kptsT   = ws + OFF_KPT;
    float* logitsT = ws + OFF_A;
    float* ocat    = ws + OFF_OCAT;
    float* wcat    = ws + OFF_WCAT;
    float* bcat    = ws + OFF_BCAT;
    float* part    = ws + OFF_PART;
    float* praw_q  = ws + OFF_PRAWQ;
    float* praw_kv = ws + OFF_PRAWK;

    k_wcat<<<dim3(1733), dim3(256), 0, stream>>>(w_q, b_q, w_kv, b_kv, w_qp, b_qp, w_kvp, b_kvp, wcat, bcat);
    k_proj2<<<dim3(36, 16), dim3(256), 0, stream>>>(s, wcat, bcat, q, kkT, vcomb, praw_q, praw_kv);
    k_rot<<<dim3(384), dim3(256), 0, stream>>>(praw_q, praw_kv, rot, trans, qp, kptsT, vcomb);
    k_bias3<<<dim3(8, NRES), dim3(256), 0, stream>>>(z, w_b, b_b, q, kkT, qp, kptsT,
        hwts, mask, logitsT);
    k_row5<<<dim3(NRES), dim3(256), 0, stream>>>(z, logitsT, vcomb, rot, trans, ocat);
    k_out2<<<dim3(12, 16, 6), dim3(256), 0, stream>>>(ocat, w_out, part);
    k_red<<<dim3(768), dim3(256), 0, stream>>>(part, b_out, out);
}

// Round 12
// 167.184 us; speedup vs baseline: 1.3001x; 1.0401x over previous
//
#include <hip/hip_runtime.h>
#include <math.h>

#define NRES 512
#define CSD  384
#define CZD  128

// workspace layout (float offsets)
#define OFF_Q     0         //  512*192
#define OFF_KT    98304     //  192*512   kkT[c][k]
#define OFF_VC    196608    //  512*512   vcomb[k][u]
#define OFF_QP    458752    //  512*144   q_pts row-major
#define OFF_KPT   532480    //  144*512   kptsT[dim][k]
#define OFF_A     606208    //  3145728: logitsT[h][q][k] (k_bias4->k_row6), then part (k_out2->k_red)
#define OFF_OCAT  3751936   //  512*2112
#define OFF_WCAT  4833280   //  384*1152 wcat + 1152 bcat
#define OFF_BCAT  (OFF_WCAT + 442368)
#define OFF_PRAWQ 5276800   //  512*144 (k_proj2 -> k_rot)
#define OFF_PRAWK 5350528   //  512*432
#define OFF_WBT   5571712   //  12*128 transposed w_b
#define OFF_PART  OFF_A     //  6*196608 (k_out2 -> k_red)

// ---------------------------------------------------------------- weight concat (+ wbT transpose)
__global__ __launch_bounds__(256) void k_wcat(
    const float* __restrict__ w_q, const float* __restrict__ b_q,
    const float* __restrict__ w_kv, const float* __restrict__ b_kv,
    const float* __restrict__ w_qp, const float* __restrict__ b_qp,
    const float* __restrict__ w_kvp, const float* __restrict__ b_kvp,
    const float* __restrict__ w_b,
    float* __restrict__ wcat, float* __restrict__ bcat, float* __restrict__ wbT)
{
    const int idx = blockIdx.x * 256 + threadIdx.x;
    if (idx < 442368) {
        const int k = idx / 1152, c = idx % 1152;
        float v;
        if (c < 192)      v = w_q[k*192 + c];
        else if (c < 576) v = w_kv[k*384 + (c - 192)];
        else if (c < 720) v = w_qp[k*144 + (c - 576)];
        else              v = w_kvp[k*432 + (c - 720)];
        wcat[idx] = v;
    } else if (idx < 443520) {
        const int c = idx - 442368;
        float v;
        if (c < 192)      v = b_q[c];
        else if (c < 576) v = b_kv[c - 192];
        else if (c < 720) v = b_qp[c - 576];
        else              v = b_kvp[c - 720];
        bcat[c] = v;
    } else if (idx < 445056) {
        const int j = idx - 443520;
        const int h = j >> 7, c = j & 127;
        wbT[h*128 + c] = w_b[c*12 + h];
    }
}

// ---------------------------------------------------------------- projections GEMM
__global__ __launch_bounds__(256) void k_proj2(
    const float* __restrict__ s, const float* __restrict__ wcat, const float* __restrict__ bcat,
    float* __restrict__ q, float* __restrict__ kkT, float* __restrict__ vcomb,
    float* __restrict__ praw_q, float* __restrict__ praw_kv)
{
    const int ct = blockIdx.x;
    const int n0 = blockIdx.y * 32;
    const int t = threadIdx.x;

    __shared__ float sT[32][34];
    __shared__ float wt[32][36];

    const int lr = t >> 3, lc4 = t & 7;
    const int tr = t >> 4, tc = t & 15;
    float4 sv4, wv4;

    sv4 = *(const float4*)&s[(n0 + lr) * CSD + lc4 * 4];
    wv4 = *(const float4*)&wcat[lr * 1152 + ct * 32 + lc4 * 4];
    sT[lc4*4+0][lr] = sv4.x; sT[lc4*4+1][lr] = sv4.y; sT[lc4*4+2][lr] = sv4.z; sT[lc4*4+3][lr] = sv4.w;
    *(float4*)&wt[lr][lc4*4] = wv4;
    __syncthreads();

    float a00 = 0.f, a01 = 0.f, a10 = 0.f, a11 = 0.f;

    for (int it = 0; it < 12; ++it) {
        if (it < 11) {
            const int k0 = (it + 1) * 32;
            sv4 = *(const float4*)&s[(n0 + lr) * CSD + k0 + lc4 * 4];
            wv4 = *(const float4*)&wcat[(k0 + lr) * 1152 + ct * 32 + lc4 * 4];
        }
        #pragma unroll
        for (int kx = 0; kx < 32; ++kx) {
            float2 ss = *(const float2*)&sT[kx][tr * 2];
            float2 ww = *(const float2*)&wt[kx][tc * 2];
            a00 += ss.x * ww.x; a01 += ss.x * ww.y;
            a10 += ss.y * ww.x; a11 += ss.y * ww.y;
        }
        __syncthreads();
        if (it < 11) {
            sT[lc4*4+0][lr] = sv4.x; sT[lc4*4+1][lr] = sv4.y; sT[lc4*4+2][lr] = sv4.z; sT[lc4*4+3][lr] = sv4.w;
            *(float4*)&wt[lr][lc4*4] = wv4;
            __syncthreads();
        }
    }

    float accv[2][2] = {{a00, a01}, {a10, a11}};
    #pragma unroll
    for (int i = 0; i < 2; ++i) {
        const int n = n0 + tr * 2 + i;
        #pragma unroll
        for (int j = 0; j < 2; ++j) {
            const int gcol = ct * 32 + tc * 2 + j;
            const float v = accv[i][j] + bcat[gcol];
            if (gcol < 192) {
                q[n*192 + gcol] = v;
            } else if (gcol < 576) {
                int g = gcol - 192, h = g >> 5, cc = g & 31;
                if (cc < 16) kkT[(h*16 + cc)*NRES + n] = v;
                else         vcomb[n*NRES + h*16 + (cc-16)] = v;
            } else if (gcol < 720) {
                praw_q[n*144 + (gcol - 576)] = v;
            } else {
                praw_kv[n*432 + (gcol - 720)] = v;
            }
        }
    }
}

// ---------------------------------------------------------------- rigid-frame rotation
__global__ __launch_bounds__(256) void k_rot(
    const float* __restrict__ praw_q, const float* __restrict__ praw_kv,
    const float* __restrict__ rot, const float* __restrict__ trans,
    float* __restrict__ q_pts, float* __restrict__ kptsT, float* __restrict__ vcomb)
{
    const int idx = blockIdx.x * 256 + threadIdx.x;
    const int n = idx / 192, u = idx % 192;
    const float* R = rot + n*9;
    const float* T = trans + n*3;
    float px, py, pz;
    if (u < 48) {
        px = praw_q[n*144 + u]; py = praw_q[n*144 + 48 + u]; pz = praw_q[n*144 + 96 + u];
    } else {
        int pt = u - 48;
        px = praw_kv[n*432 + pt]; py = praw_kv[n*432 + 144 + pt]; pz = praw_kv[n*432 + 288 + pt];
    }
    float x  = R[0]*px + R[1]*py + R[2]*pz + T[0];
    float y  = R[3]*px + R[4]*py + R[5]*pz + T[1];
    float zc = R[6]*px + R[7]*py + R[8]*pz + T[2];
    if (u < 48) {
        int o = (n*48 + u)*3;
        q_pts[o] = x; q_pts[o+1] = y; q_pts[o+2] = zc;
    } else {
        int pt = u - 48;
        int h = pt / 12, pp = pt % 12;
        if (pp < 4) {
            int dim = (h*4 + pp)*3;
            kptsT[(dim+0)*NRES + n] = x;
            kptsT[(dim+1)*NRES + n] = y;
            kptsT[(dim+2)*NRES + n] = zc;
        } else {
            int u2 = (h*8 + (pp-4))*3;
            vcomb[n*NRES + 192 + u2+0] = x;
            vcomb[n*NRES + 192 + u2+1] = y;
            vcomb[n*NRES + 192 + u2+2] = zc;
        }
    }
}

// ---------------------------------------------------------------- z pass 1: bias + full logits
// grid (8 k-chunks, 512 q). Correct st-style swizzle (slot ^= row&7); wb from GLOBAL (broadcast);
// thread = 4 k (stride-16) x 32 c x 3 h, wb regs amortized over k.
__global__ __launch_bounds__(256) void k_bias4(
    const float* __restrict__ z, const float* __restrict__ wbT, const float* __restrict__ b_b,
    const float* __restrict__ q, const float* __restrict__ kkT,
    const float* __restrict__ q_pts, const float* __restrict__ kptsT,
    const float* __restrict__ head_weights, const float* __restrict__ mask,
    float* __restrict__ logitsT)
{
    const int k0 = blockIdx.x * 64;
    const int qn = blockIdx.y;
    const int t = threadIdx.x;
    __shared__ float zt[64*128];         // float4-slot sc4 = c4 ^ (row&7)
    __shared__ float part[4][64][13];
    __shared__ float q_lds[192];
    __shared__ float qp_lds[144];
    __shared__ float hw_lds[12];

    // stage z tile (coalesced loads, swizzled stores)
    const float4* zp4 = (const float4*)(z + ((size_t)qn*NRES + k0)*CZD);
    float4 zstg[8];
    #pragma unroll
    for (int r = 0; r < 8; ++r) zstg[r] = zp4[t + r*256];
    #pragma unroll
    for (int r = 0; r < 8; ++r) {
        const int idx = t + r*256;
        const int row = idx >> 5, c4 = idx & 31;
        const int sc4 = c4 ^ (row & 7);
        *(float4*)&zt[row*128 + sc4*4] = zstg[r];
    }
    if (t < 192) q_lds[t] = q[qn*192 + t];
    if (t < 144) qp_lds[t] = q_pts[qn*144 + t];
    if (t < 12)  hw_lds[t] = logf(1.f + expf(head_weights[t])) * 0.13608276f;
    __syncthreads();

    // bias compute: kgrp = t&15 (k = kgrp+16*kk), cgrp = (t>>4)&3, hgrp = t>>6
    {
        const int kgrp = t & 15, cgrp = (t >> 4) & 3, hgrp = t >> 6;
        const int h0 = hgrp * 3;
        const int kx7 = kgrp & 7;
        const float* w0 = wbT + (h0+0)*128 + cgrp*32;
        const float* w1 = wbT + (h0+1)*128 + cgrp*32;
        const float* w2 = wbT + (h0+2)*128 + cgrp*32;
        float acc[4][3];
        #pragma unroll
        for (int kk = 0; kk < 4; ++kk)
            #pragma unroll
            for (int j = 0; j < 3; ++j) acc[kk][j] = 0.f;
        #pragma unroll
        for (int j = 0; j < 8; ++j) {
            const int c4 = cgrp*8 + j;
            const float4 wa  = *(const float4*)&w0[j*4];   // global, wave-broadcast, L1-hit
            const float4 wbv = *(const float4*)&w1[j*4];
            const float4 wc  = *(const float4*)&w2[j*4];
            const int sc4 = c4 ^ kx7;
            #pragma unroll
            for (int kk = 0; kk < 4; ++kk) {
                const int k = kgrp + 16*kk;
                float4 zv = *(const float4*)&zt[k*128 + sc4*4];
                acc[kk][0] += zv.x*wa.x  + zv.y*wa.y  + zv.z*wa.z  + zv.w*wa.w;
                acc[kk][1] += zv.x*wbv.x + zv.y*wbv.y + zv.z*wbv.z + zv.w*wbv.w;
                acc[kk][2] += zv.x*wc.x  + zv.y*wc.y  + zv.z*wc.z  + zv.w*wc.w;
            }
        }
        #pragma unroll
        for (int kk = 0; kk < 4; ++kk)
            #pragma unroll
            for (int j = 0; j < 3; ++j)
                part[cgrp][kgrp + 16*kk][h0 + j] = acc[kk][j];
    }
    __syncthreads();

    // logits: thread = k (t&63), heads h0..h0+2 (t>>6)
    {
        const int k = t & 63;
        const int h0 = (t >> 6) * 3;
        const int kn = k0 + k;
        const float mterm = (mask[qn]*mask[kn] - 1.f) * 100000.f;
        float biasv[3];
        #pragma unroll
        for (int j = 0; j < 3; ++j)
            biasv[j] = b_b[h0+j] + part[0][k][h0+j] + part[1][k][h0+j]
                     + part[2][k][h0+j] + part[3][k][h0+j];
        #pragma unroll
        for (int j = 0; j < 3; ++j) {
            const int h = h0 + j;
            float qk = 0.f;
            const float* kT = kkT + (size_t)(h*16)*NRES + kn;
            #pragma unroll
            for (int c = 0; c < 16; ++c) qk += q_lds[h*16 + c] * kT[(size_t)c*NRES];
            float dsum = 0.f;
            const float* kpT = kptsT + (size_t)(h*12)*NRES + kn;
            #pragma unroll
            for (int d = 0; d < 12; ++d) { float df = qp_lds[h*12 + d] - kpT[(size_t)d*NRES]; dsum += df*df; }
            logitsT[(size_t)h*NRES*NRES + (size_t)qn*NRES + kn] =
                0.14433757f*qk + 0.57735027f*biasv[j] - 0.5f*hw_lds[h]*dsum + mterm;
        }
    }
}

// ---------------------------------------------------------------- per-q-row: softmax + o_pair + o/o_pt + rot
// a stored k-major aT[512][20] -> o_pair reads 3 broadcast b128 per kn; intra-wave shfl reduce (no pred buffer).
__global__ __launch_bounds__(256) void k_row6(
    const float* __restrict__ z, const float* __restrict__ logitsT,
    const float* __restrict__ vcomb,
    const float* __restrict__ rot, const float* __restrict__ trans,
    float* __restrict__ o_cat)
{
    const int qn = blockIdx.x;
    const int t = threadIdx.x;

    __shared__ float aT[512*20];    // row kn: heads 0..11, pad to 20
    __shared__ float optraw[288];

    // load logits (coalesced global) into k-major layout
    for (int i = t; i < 12*NRES; i += 256) {
        const int h = i >> 9, kn = i & 511;
        aT[kn*20 + h] = logitsT[(size_t)h*NRES*NRES + (size_t)qn*NRES + kn];
    }
    __syncthreads();

    // softmax per head (3 heads/wave), values held in regs between passes
    {
        const int w = t >> 6, lane = t & 63;
        for (int h = w; h < 12; h += 4) {
            float v[8];
            float m = -1e30f;
            #pragma unroll
            for (int i = 0; i < 8; ++i) {
                v[i] = aT[(lane + i*64)*20 + h];
                m = fmaxf(m, v[i]);
            }
            #pragma unroll
            for (int off = 32; off > 0; off >>= 1) m = fmaxf(m, __shfl_xor(m, off));
            float ss = 0.f;
            #pragma unroll
            for (int i = 0; i < 8; ++i) { v[i] = __expf(v[i] - m); ss += v[i]; }
            #pragma unroll
            for (int off = 32; off > 0; off >>= 1) ss += __shfl_xor(ss, off);
            const float inv = 1.f / ss;
            #pragma unroll
            for (int i = 0; i < 8; ++i) aT[(lane + i*64)*20 + h] = v[i] * inv;
        }
    }
    __syncthreads();

    // o_pair: wave w owns c4 in [w*8, w*8+8); lane = c4i(3b) | kg(3b); reduce over kg via shfl
    {
        const int lane = t & 63, w = t >> 6;
        const int c4 = w*8 + (lane & 7);
        const int kg = lane >> 3;
        const float4* zp = (const float4*)(z + (size_t)qn*NRES*CZD) + c4;
        float4 acc4[12];
        #pragma unroll
        for (int h = 0; h < 12; ++h) acc4[h] = make_float4(0.f,0.f,0.f,0.f);

        #pragma unroll 4
        for (int i = 0; i < 64; ++i) {
            const int kn = kg + 8*i;
            float4 zv = zp[(size_t)kn*32];
            float4 a0 = *(const float4*)&aT[kn*20 + 0];
            float4 a1 = *(const float4*)&aT[kn*20 + 4];
            float4 a2 = *(const float4*)&aT[kn*20 + 8];
            float av[12] = {a0.x,a0.y,a0.z,a0.w, a1.x,a1.y,a1.z,a1.w, a2.x,a2.y,a2.z,a2.w};
            #pragma unroll
            for (int h = 0; h < 12; ++h) {
                acc4[h].x += av[h]*zv.x; acc4[h].y += av[h]*zv.y;
                acc4[h].z += av[h]*zv.z; acc4[h].w += av[h]*zv.w;
            }
        }
        #pragma unroll
        for (int h = 0; h < 12; ++h) {
            #pragma unroll
            for (int off = 8; off < 64; off <<= 1) {
                acc4[h].x += __shfl_xor(acc4[h].x, off);
                acc4[h].y += __shfl_xor(acc4[h].y, off);
                acc4[h].z += __shfl_xor(acc4[h].z, off);
                acc4[h].w += __shfl_xor(acc4[h].w, off);
            }
        }
        if (kg == 0) {
            float* ob = o_cat + qn*2112 + 576;
            #pragma unroll
            for (int h = 0; h < 12; ++h)
                *(float4*)&ob[h*128 + c4*4] = acc4[h];
        }
    }

    // o (192) + o_pt raw (288) from vcomb (L2), float2 per thread
    if (t < 240) {
        const int ch0 = 2*t, ch1 = 2*t + 1;
        const int hA = (ch0 < 192) ? (ch0 >> 4) : (ch0 - 192) / 24;
        const int hB = (ch1 < 192) ? (ch1 >> 4) : (ch1 - 192) / 24;
        float aAcc = 0.f, bAcc = 0.f;
        const float2* vp2 = (const float2*)vcomb + t;
        #pragma unroll 8
        for (int kn = 0; kn < NRES; ++kn) {
            float2 v = vp2[(size_t)kn*256];
            aAcc += aT[kn*20 + hA] * v.x;
            bAcc += aT[kn*20 + hB] * v.y;
        }
        if (ch0 < 192) o_cat[qn*2112 + ch0] = aAcc;
        else           optraw[ch0 - 192] = aAcc;
        if (ch1 < 192) o_cat[qn*2112 + ch1] = bAcc;
        else           optraw[ch1 - 192] = bAcc;
    }
    __syncthreads();

    // inverse rotation + norms
    if (t < 96) {
        const float* R = rot + qn*9;
        const float* T = trans + qn*3;
        float ox = optraw[t*3]   - T[0];
        float oy = optraw[t*3+1] - T[1];
        float oz = optraw[t*3+2] - T[2];
        float x  = R[0]*ox + R[3]*oy + R[6]*oz;
        float y  = R[1]*ox + R[4]*oy + R[7]*oz;
        float zc = R[2]*ox + R[5]*oy + R[8]*oz;
        float* ob = o_cat + qn*2112;
        ob[192 + t] = x;
        ob[288 + t] = y;
        ob[384 + t] = zc;
        ob[480 + t] = sqrtf(x*x + y*y + zc*zc + 1e-8f);
    }
}

// ---------------------------------------------------------------- final GEMM
__global__ __launch_bounds__(256) void k_out2(
    const float* __restrict__ o_cat, const float* __restrict__ w_out, float* __restrict__ part)
{
    const int ct = blockIdx.x;
    const int n0 = blockIdx.y * 32;
    const int kc = blockIdx.z;
    const int t = threadIdx.x;

    __shared__ float oT[32][34];
    __shared__ float wt[32][36];

    const int lr = t >> 3, lc4 = t & 7;
    const int tr = t >> 4, tc = t & 15;
    const int kbase = kc * 352;
    float4 ov4, wv4;

    ov4 = *(const float4*)&o_cat[(n0 + lr) * 2112 + kbase + lc4 * 4];
    wv4 = *(const float4*)&w_out[(kbase + lr) * 384 + ct * 32 + lc4 * 4];
    oT[lc4*4+0][lr] = ov4.x; oT[lc4*4+1][lr] = ov4.y; oT[lc4*4+2][lr] = ov4.z; oT[lc4*4+3][lr] = ov4.w;
    *(float4*)&wt[lr][lc4*4] = wv4;
    __syncthreads();

    float a00 = 0.f, a01 = 0.f, a10 = 0.f, a11 = 0.f;

    for (int it = 0; it < 11; ++it) {
        if (it < 10) {
            const int k0 = kbase + (it + 1) * 32;
            ov4 = *(const float4*)&o_cat[(n0 + lr) * 2112 + k0 + lc4 * 4];
            wv4 = *(const float4*)&w_out[(k0 + lr) * 384 + ct * 32 + lc4 * 4];
        }
        #pragma unroll
        for (int kx = 0; kx < 32; ++kx) {
            float2 oo = *(const float2*)&oT[kx][tr * 2];
            float2 ww = *(const float2*)&wt[kx][tc * 2];
            a00 += oo.x * ww.x; a01 += oo.x * ww.y;
            a10 += oo.y * ww.x; a11 += oo.y * ww.y;
        }
        __syncthreads();
        if (it < 10) {
            oT[lc4*4+0][lr] = ov4.x; oT[lc4*4+1][lr] = ov4.y; oT[lc4*4+2][lr] = ov4.z; oT[lc4*4+3][lr] = ov4.w;
            *(float4*)&wt[lr][lc4*4] = wv4;
            __syncthreads();
        }
    }

    float* pp = part + (size_t)kc * 196608;
    pp[(n0 + tr*2 + 0)*384 + ct*32 + tc*2 + 0] = a00;
    pp[(n0 + tr*2 + 0)*384 + ct*32 + tc*2 + 1] = a01;
    pp[(n0 + tr*2 + 1)*384 + ct*32 + tc*2 + 0] = a10;
    pp[(n0 + tr*2 + 1)*384 + ct*32 + tc*2 + 1] = a11;
}

__global__ __launch_bounds__(256) void k_red(
    const float* __restrict__ part, const float* __restrict__ b_out, float* __restrict__ out)
{
    const int i = blockIdx.x*256 + threadIdx.x;
    float acc = b_out[i % 384];
    #pragma unroll
    for (int dc = 0; dc < 6; ++dc) acc += part[(size_t)dc*196608 + i];
    out[i] = acc;
}

// ----------------------------------------------------------------
extern "C" void kernel_launch(void* const* d_in, const int* in_sizes, int n_in,
                              void* d_out, int out_size, void* d_ws, size_t ws_size,
                              hipStream_t stream) {
    (void)in_sizes; (void)n_in; (void)out_size; (void)ws_size;
    const float* s      = (const float*)d_in[0];
    const float* z      = (const float*)d_in[1];
    const float* rot    = (const float*)d_in[2];
    const float* trans  = (const float*)d_in[3];
    const float* mask   = (const float*)d_in[4];
    const float* w_q    = (const float*)d_in[5];
    const float* b_q    = (const float*)d_in[6];
    const float* w_kv   = (const float*)d_in[7];
    const float* b_kv   = (const float*)d_in[8];
    const float* w_qp   = (const float*)d_in[9];
    const float* b_qp   = (const float*)d_in[10];
    const float* w_kvp  = (const float*)d_in[11];
    const float* b_kvp  = (const float*)d_in[12];
    const float* w_b    = (const float*)d_in[13];
    const float* b_b    = (const float*)d_in[14];
    const float* hwts   = (const float*)d_in[15];
    const float* w_out  = (const float*)d_in[16];
    const float* b_out  = (const float*)d_in[17];
    float* out = (float*)d_out;
    float* ws  = (float*)d_ws;

    float* q       = ws + OFF_Q;
    float* kkT     = ws + OFF_KT;
    float* vcomb   = ws + OFF_VC;
    float* qp      = ws + OFF_QP;
    float* kptsT   = ws + OFF_KPT;
    float* logitsT = ws + OFF_A;
    float* ocat    = ws + OFF_OCAT;
    float* wcat    = ws + OFF_WCAT;
    float* bcat    = ws + OFF_BCAT;
    float* wbT     = ws + OFF_WBT;
    float* part    = ws + OFF_PART;
    float* praw_q  = ws + OFF_PRAWQ;
    float* praw_kv = ws + OFF_PRAWK;

    k_wcat<<<dim3(1739), dim3(256), 0, stream>>>(w_q, b_q, w_kv, b_kv, w_qp, b_qp, w_kvp, b_kvp,
        w_b, wcat, bcat, wbT);
    k_proj2<<<dim3(36, 16), dim3(256), 0, stream>>>(s, wcat, bcat, q, kkT, vcomb, praw_q, praw_kv);
    k_rot<<<dim3(384), dim3(256), 0, stream>>>(praw_q, praw_kv, rot, trans, qp, kptsT, vcomb);
    k_bias4<<<dim3(8, NRES), dim3(256), 0, stream>>>(z, wbT, b_b, q, kkT, qp, kptsT,
        hwts, mask, logitsT);
    k_row6<<<dim3(NRES), dim3(256), 0, stream>>>(z, logitsT, vcomb, rot, trans, ocat);
    k_out2<<<dim3(12, 16, 6), dim3(256), 0, stream>>>(ocat, w_out, part);
    k_red<<<dim3(768), dim3(256), 0, stream>>>(part, b_out, out);
}